// Round 1
// baseline (9.616 us; speedup 1.0000x reference)
//
#include <hip/hip_runtime.h>

// QNN collapses analytically: probabilities are a permutation of the product
// state's (RZ phases cancel in |.|^2; weights input is provably unused), and
// the GF(2)-linear CNOT-ring permutation factorizes each expectation into a
// product of per-qubit cos(enc_offset[m] + enc_scale[m]*x[m]).
// Masks (qubit subsets), verified by 24-step mask simulation of the ring x3:
//   S0={1,4,5} S1={1,2,4,6} S2={2,3,5,7} S3={0,3,4,6} S4={0,1,4,5,7}
//   S5={1,2,5,6} S6={2,3,6,7} S7={0,3,4,7}  S_parity={0,4}

__global__ __launch_bounds__(256) void qnn_kernel(
    const float* __restrict__ x,    // (B, 8)
    const float* __restrict__ off,  // (8,)
    const float* __restrict__ sc,   // (8,)
    const float* __restrict__ W,    // (2, 9) row-major
    const float* __restrict__ bias, // (2,)
    float* __restrict__ out,        // (B, 2)
    int B)
{
    int i = blockIdx.x * blockDim.x + threadIdx.x;
    if (i >= B) return;

    // 32 contiguous bytes per thread -> two float4 loads, fully coalesced
    const float4* xv = reinterpret_cast<const float4*>(x + (size_t)i * 8);
    float4 xa = xv[0];
    float4 xb = xv[1];
    float xs[8] = {xa.x, xa.y, xa.z, xa.w, xb.x, xb.y, xb.z, xb.w};

    float c[8];
#pragma unroll
    for (int m = 0; m < 8; ++m) {
        // a_m = off[m] + sc[m]*x[m]; uniform-address loads -> scalarized
        c[m] = __cosf(fmaf(sc[m], xs[m], off[m]));
    }

    // shared partials
    float c14 = c[1] * c[4];
    float c23 = c[2] * c[3];
    float c04 = c[0] * c[4];

    float f[9];
    f[0] = c14 * c[5];               // c1 c4 c5
    f[1] = c14 * c[2] * c[6];        // c1 c2 c4 c6
    f[2] = c23 * c[5] * c[7];        // c2 c3 c5 c7
    f[3] = c04 * c[3] * c[6];        // c0 c3 c4 c6
    f[4] = c04 * c[1] * c[5] * c[7]; // c0 c1 c4 c5 c7
    f[5] = c[1] * c[2] * c[5] * c[6];
    f[6] = c23 * c[6] * c[7];        // c2 c3 c6 c7
    f[7] = c04 * c[3] * c[7];        // c0 c3 c4 c7
    f[8] = c04;                      // parity: c0 c4

    float o0 = bias[0];
    float o1 = bias[1];
#pragma unroll
    for (int k = 0; k < 9; ++k) {
        o0 = fmaf(f[k], W[k], o0);
        o1 = fmaf(f[k], W[9 + k], o1);
    }

    reinterpret_cast<float2*>(out)[i] = make_float2(o0, o1);
}

extern "C" void kernel_launch(void* const* d_in, const int* in_sizes, int n_in,
                              void* d_out, int out_size, void* d_ws, size_t ws_size,
                              hipStream_t stream)
{
    // setup_inputs order: x, weights (unused — phases cancel), enc_offset,
    // enc_scale, W, b
    const float* x    = (const float*)d_in[0];
    const float* off  = (const float*)d_in[2];
    const float* sc   = (const float*)d_in[3];
    const float* W    = (const float*)d_in[4];
    const float* bias = (const float*)d_in[5];
    float* out = (float*)d_out;

    int B = in_sizes[0] / 8;
    int threads = 256;
    int blocks = (B + threads - 1) / threads;
    qnn_kernel<<<blocks, threads, 0, stream>>>(x, off, sc, W, bias, out, B);
}